// Round 8
// baseline (179.655 us; speedup 1.0000x reference)
//
#include <hip/hip_runtime.h>
#include <math.h>

#define UDIM 512
#define DIN  256
#define BATCH 128
#define EPSV 1e-3f

typedef float f4 __attribute__((ext_vector_type(4)));

// ---------------------------------------------------------------------------
// K1: pre = prev @ W_h + inputs @ C ; h = tanh(pre + bias)
// ---------------------------------------------------------------------------
__global__ __launch_bounds__(256) void k_pre(
    const float* __restrict__ inputs, const float* __restrict__ prev,
    const float* __restrict__ C, const float* __restrict__ Wh,
    const float* __restrict__ bias, float* __restrict__ pre, float* __restrict__ h)
{
    const int b = blockIdx.x >> 1;
    const int v = ((blockIdx.x & 1) << 8) + threadIdx.x;

    __shared__ float sprev[UDIM];
    __shared__ float sinp[DIN];
    for (int i = threadIdx.x; i < UDIM; i += 256) sprev[i] = prev[b * UDIM + i];
    sinp[threadIdx.x] = inputs[b * DIN + threadIdx.x];
    __syncthreads();

    float acc = 0.f;
#pragma unroll 8
    for (int u = 0; u < UDIM; ++u) acc = fmaf(sprev[u], Wh[u * UDIM + v], acc);
#pragma unroll 8
    for (int i = 0; i < DIN; ++i)  acc = fmaf(sinp[i], C[i * UDIM + v], acc);

    pre[b * UDIM + v] = acc;
    h[b * UDIM + v]   = tanhf(acc + bias[v]);
}

// ---------------------------------------------------------------------------
// K2: 256 blocks x 1024 threads, two independent roles:
//  W-blocks (bid>=128): Anew = 0.9A + 0.5 h h^T   (NT load + NT store;
//      Anew is never read -> keep it out of L3 so L3 retains A)
//  R-blocks (bid<128): whole-batch 3-step recurrence using the identity
//      x@Anew = 0.9*(x@A) + 0.5*(x.h)*h   -- reads A only, LN block-local.
// ---------------------------------------------------------------------------
__global__ __launch_bounds__(1024) void k_main(
    const float* __restrict__ A, const float* __restrict__ pre,
    const float* __restrict__ h, const float* __restrict__ gamma,
    const float* __restrict__ beta, float* __restrict__ Anew,
    float* __restrict__ out)
{
    const int t    = threadIdx.x;
    const int vg   = t & 127;       // 128 col-groups x 4 = 512 cols
    const int col  = vg << 2;
    const int rseg = t >> 7;        // 0..7 row segments x 64 rows
    const int row0 = rseg * 64;

    if (blockIdx.x >= BATCH) {
        // ---------------- W-role: write A_new, nontemporal both ways -------
        const int b = blockIdx.x - BATCH;
        __shared__ __align__(16) float wsh[UDIM];
        if (t < UDIM) wsh[t] = h[(size_t)b * UDIM + t];
        __syncthreads();
        const f4 hv4 = *(const f4*)(wsh + col);
        const float* __restrict__ Ab  = A    + ((size_t)b * UDIM + row0) * UDIM + col;
        float*       __restrict__ Anb = Anew + ((size_t)b * UDIM + row0) * UDIM + col;
        for (int g = 0; g < 8; ++g) {
            f4 buf[8];
#pragma unroll
            for (int j = 0; j < 8; ++j)
                buf[j] = __builtin_nontemporal_load(
                    (const f4*)(Ab + (size_t)(g * 8 + j) * UDIM));
#pragma unroll
            for (int j = 0; j < 8; ++j) {
                const float s = 0.5f * wsh[row0 + g * 8 + j];
                f4 an;
                an.x = fmaf(s, hv4.x, 0.9f * buf[j].x);
                an.y = fmaf(s, hv4.y, 0.9f * buf[j].y);
                an.z = fmaf(s, hv4.z, 0.9f * buf[j].z);
                an.w = fmaf(s, hv4.w, 0.9f * buf[j].w);
                __builtin_nontemporal_store(an, (f4*)(Anb + (size_t)(g * 8 + j) * UDIM));
            }
        }
        return;
    }

    // ---------------- R-role: 3-step recurrence on batch b -----------------
    const int b    = blockIdx.x;
    const int lane = t & 63;
    const int wave = t >> 6;        // 0..15

    __shared__ __align__(16) float sh[UDIM];       // h (fixed)
    __shared__ __align__(16) float sx[UDIM];       // current state x
    __shared__ __align__(16) float spart[8][UDIM]; // matvec partials
    __shared__ float sred[16];
    __shared__ float sbc[4];                       // 0:mean 1:rstd 2:dot

    float prereg = 0.f, gam = 0.f, bet = 0.f;
    if (t < UDIM) {
        const float hv = h[(size_t)b * UDIM + t];
        sh[t] = hv; sx[t] = hv;
        prereg = pre[(size_t)b * UDIM + t];
        gam = gamma[t]; bet = beta[t];
    }
    __syncthreads();

    const float* __restrict__ Ab = A + ((size_t)b * UDIM + row0) * UDIM + col;

    for (int step = 0; step < 3; ++step) {
        // ---- dot = x . h ----
        {
            float p = (t < UDIM) ? sx[t] * sh[t] : 0.f;
#pragma unroll
            for (int off = 32; off; off >>= 1) p += __shfl_xor(p, off, 64);
            if (lane == 0) sred[wave] = p;
            __syncthreads();
            if (t == 0) {
                float d = 0.f;
#pragma unroll
                for (int i = 0; i < 16; ++i) d += sred[i];
                sbc[2] = d;
            }
            __syncthreads();
        }

        // ---- acc = x @ A  (8-deep load batching for MLP) ----
        f4 acc = {0.f, 0.f, 0.f, 0.f};
        for (int g = 0; g < 8; ++g) {
            f4 buf[8];
#pragma unroll
            for (int j = 0; j < 8; ++j)
                buf[j] = *(const f4*)(Ab + (size_t)(g * 8 + j) * UDIM);
#pragma unroll
            for (int j = 0; j < 8; ++j) {
                const float xu = sx[row0 + g * 8 + j];
                acc.x = fmaf(xu, buf[j].x, acc.x);
                acc.y = fmaf(xu, buf[j].y, acc.y);
                acc.z = fmaf(xu, buf[j].z, acc.z);
                acc.w = fmaf(xu, buf[j].w, acc.w);
            }
        }
        *(f4*)(&spart[rseg][col]) = acc;
        __syncthreads();

        // ---- combine, tanh, layernorm (threads 0..511) ----
        float hs = 0.f;
        if (t < UDIM) {
            float y = 0.f;
#pragma unroll
            for (int s = 0; s < 8; ++s) y += spart[s][t];
            y = fmaf(0.9f, y, 0.5f * sbc[2] * sh[t]);
            hs = tanhf(prereg + y);
            float s1 = hs, s2 = hs * hs;
#pragma unroll
            for (int off = 32; off; off >>= 1) {
                s1 += __shfl_xor(s1, off, 64);
                s2 += __shfl_xor(s2, off, 64);
            }
            if (lane == 0) { sred[wave] = s1; sred[8 + wave] = s2; }
        }
        __syncthreads();
        if (t == 0) {
            float m = 0.f, q = 0.f;
#pragma unroll
            for (int i = 0; i < 8; ++i) { m += sred[i]; q += sred[8 + i]; }
            m *= (1.f / UDIM);
            q = q * (1.f / UDIM) - m * m;
            sbc[0] = m;
            sbc[1] = rsqrtf(q + EPSV);
        }
        __syncthreads();
        if (t < UDIM) {
            const float xn = (hs - sbc[0]) * sbc[1] * gam + bet;
            if (step == 2) out[(size_t)b * UDIM + t] = xn;
            else           sx[t] = xn;
        }
        __syncthreads();
    }
}

// ---------------------------------------------------------------------------
extern "C" void kernel_launch(void* const* d_in, const int* in_sizes, int n_in,
                              void* d_out, int out_size, void* d_ws, size_t ws_size,
                              hipStream_t stream) {
    const float* inputs = (const float*)d_in[0];
    const float* prev   = (const float*)d_in[1];
    const float* A      = (const float*)d_in[2];
    const float* C      = (const float*)d_in[3];
    const float* Wh     = (const float*)d_in[4];
    const float* bias   = (const float*)d_in[5];
    const float* gamma  = (const float*)d_in[6];
    const float* beta   = (const float*)d_in[7];

    float* out  = (float*)d_out;                 // (128,512)
    float* Anew = out + (size_t)BATCH * UDIM;    // (128,512,512)

    float* pre = (float*)d_ws;                   // 128*512
    float* h   = pre + (size_t)BATCH * UDIM;     // 128*512

    k_pre <<<BATCH * 2, 256, 0, stream>>>(inputs, prev, C, Wh, bias, pre, h);
    k_main<<<BATCH * 2, 1024, 0, stream>>>(A, pre, h, gamma, beta, Anew, out);
}

// Round 9
// 127.223 us; speedup vs baseline: 1.4121x; 1.4121x over previous
//
#include <hip/hip_runtime.h>
#include <math.h>

#define UDIM 512
#define DIN  256
#define BATCH 128
#define EPSV 1e-3f
#define NSLAB 8      // blocks per batch
#define RPB   64     // rows per block-slab

typedef float f4 __attribute__((ext_vector_type(4)));
typedef unsigned int  u32;
typedef unsigned int  u4  __attribute__((ext_vector_type(4)));
typedef unsigned short us4 __attribute__((ext_vector_type(4)));

__device__ inline unsigned short f2bf(float f) {          // RNE bf16
    u32 u = __float_as_uint(f);
    u32 r = u + 0x7fffu + ((u >> 16) & 1u);
    return (unsigned short)(r >> 16);
}

// ---------------------------------------------------------------------------
// K1: pre = prev @ W_h + inputs @ C ; h = tanh(pre + bias)   [proven]
// ---------------------------------------------------------------------------
__global__ __launch_bounds__(256) void k_pre(
    const float* __restrict__ inputs, const float* __restrict__ prev,
    const float* __restrict__ C, const float* __restrict__ Wh,
    const float* __restrict__ bias, float* __restrict__ pre, float* __restrict__ h)
{
    const int b = blockIdx.x >> 1;
    const int v = ((blockIdx.x & 1) << 8) + threadIdx.x;

    __shared__ float sprev[UDIM];
    __shared__ float sinp[DIN];
    for (int i = threadIdx.x; i < UDIM; i += 256) sprev[i] = prev[b * UDIM + i];
    sinp[threadIdx.x] = inputs[b * DIN + threadIdx.x];
    __syncthreads();

    float acc = 0.f;
#pragma unroll 8
    for (int u = 0; u < UDIM; ++u) acc = fmaf(sprev[u], Wh[u * UDIM + v], acc);
#pragma unroll 8
    for (int i = 0; i < DIN; ++i)  acc = fmaf(sinp[i], C[i * UDIM + v], acc);

    pre[b * UDIM + v] = acc;
    h[b * UDIM + v]   = tanhf(acc + bias[v]);
}

// ---------------------------------------------------------------------------
// K2 (pass 0): block (b,rs) streams 64 rows of A[b] once:
//   Anew = 0.9A + 0.5 h h^T  (NT store, never read again)
//   Abf  = bf16(A)           (regular store; 67 MB, read by passes 1-2)
//   ypart = h @ A  (RAW partials) ; rs==0 writes dot_hh[b]
// grid = 1024 x 256
// ---------------------------------------------------------------------------
template <int WBF>
__global__ __launch_bounds__(256) void k_p0(
    const float* __restrict__ A, const float* __restrict__ h,
    float* __restrict__ Anew, us4* __restrict__ Abf,
    float* __restrict__ ypart, float* __restrict__ dotout)
{
    const int bc   = blockIdx.x;
    const int b    = bc >> 3;
    const int rs   = bc & 7;
    const int t    = threadIdx.x;
    const int lane = t & 63;
    const int wave = t >> 6;       // 0..3
    const int vg   = t & 127;
    const int col  = vg << 2;
    const int half = t >> 7;
    const int row0 = rs * RPB + half * 32;

    __shared__ __align__(16) float sh[UDIM];
    __shared__ __align__(16) float spart[2][UDIM];
    __shared__ float sred[4];

    sh[t]       = h[(size_t)b * UDIM + t];
    sh[t + 256] = h[(size_t)b * UDIM + t + 256];
    __syncthreads();

    float dp = sh[t] * sh[t] + sh[t + 256] * sh[t + 256];
#pragma unroll
    for (int off = 32; off; off >>= 1) dp += __shfl_xor(dp, off, 64);
    if (lane == 0) sred[wave] = dp;

    const f4 hv4 = *(const f4*)(sh + col);
    const float* __restrict__ Ab  = A    + ((size_t)b * UDIM + row0) * UDIM + col;
    float*       __restrict__ Anb = Anew + ((size_t)b * UDIM + row0) * UDIM + col;
    us4*         __restrict__ Bfb = WBF ? (Abf + (((size_t)b * UDIM + row0) * UDIM + col) / 4) : nullptr;

    f4 acc = {0.f, 0.f, 0.f, 0.f};
#pragma unroll 4
    for (int k = 0; k < 32; ++k) {
        const f4 a4 = __builtin_nontemporal_load((const f4*)(Ab + (size_t)k * UDIM));
        const float hu = sh[row0 + k];
        const float s  = 0.5f * hu;
        f4 an;
        an.x = fmaf(s, hv4.x, 0.9f * a4.x);
        an.y = fmaf(s, hv4.y, 0.9f * a4.y);
        an.z = fmaf(s, hv4.z, 0.9f * a4.z);
        an.w = fmaf(s, hv4.w, 0.9f * a4.w);
        __builtin_nontemporal_store(an, (f4*)(Anb + (size_t)k * UDIM));
        if (WBF) {
            us4 bv;
            bv.x = f2bf(a4.x); bv.y = f2bf(a4.y);
            bv.z = f2bf(a4.z); bv.w = f2bf(a4.w);
            Bfb[(size_t)k * (UDIM / 4)] = bv;
        }
        acc.x = fmaf(hu, a4.x, acc.x);
        acc.y = fmaf(hu, a4.y, acc.y);
        acc.z = fmaf(hu, a4.z, acc.z);
        acc.w = fmaf(hu, a4.w, acc.w);
    }
    *(f4*)(&spart[half][col]) = acc;
    __syncthreads();

    ypart[(size_t)bc * UDIM + t]       = spart[0][t]       + spart[1][t];
    ypart[(size_t)bc * UDIM + t + 256] = spart[0][t + 256] + spart[1][t + 256];
    if (rs == 0 && t == 0)
        dotout[b] = sred[0] + sred[1] + sred[2] + sred[3];
}

// ---------------------------------------------------------------------------
// Combine (shared by both mv variants): yp,dot -> x in sx[]; new dot -> sred2
// ---------------------------------------------------------------------------
__device__ inline void combine_ln(
    int b, int t, int lane, int wave,
    const float* __restrict__ pre, const float* __restrict__ h,
    const float* __restrict__ ypin, const float* __restrict__ dotin,
    const float* __restrict__ gamma, const float* __restrict__ beta,
    float* sx, float* sred, float* sred2, float* sbc)
{
    float y0 = 0.f, y1 = 0.f;
#pragma unroll
    for (int s = 0; s < NSLAB; ++s) {
        y0 += ypin[((size_t)b * NSLAB + s) * UDIM + t];
        y1 += ypin[((size_t)b * NSLAB + s) * UDIM + t + 256];
    }
    const float h0 = h[(size_t)b * UDIM + t];
    const float h1 = h[(size_t)b * UDIM + t + 256];
    const float d  = 0.5f * dotin[b];
    y0 = fmaf(0.9f, y0, d * h0);
    y1 = fmaf(0.9f, y1, d * h1);
    const float hs0 = tanhf(pre[(size_t)b * UDIM + t]       + y0);
    const float hs1 = tanhf(pre[(size_t)b * UDIM + t + 256] + y1);
    float s1 = hs0 + hs1, s2 = hs0 * hs0 + hs1 * hs1;
#pragma unroll
    for (int off = 32; off; off >>= 1) {
        s1 += __shfl_xor(s1, off, 64);
        s2 += __shfl_xor(s2, off, 64);
    }
    if (lane == 0) { sred[wave] = s1; sred[4 + wave] = s2; }
    __syncthreads();
    if (t == 0) {
        float m = sred[0] + sred[1] + sred[2] + sred[3];
        float q = sred[4] + sred[5] + sred[6] + sred[7];
        m *= (1.f / UDIM);
        q = q * (1.f / UDIM) - m * m;
        sbc[0] = m;
        sbc[1] = rsqrtf(q + EPSV);
    }
    __syncthreads();
    const float m = sbc[0], r = sbc[1];
    const float x0 = (hs0 - m) * r * gamma[t]       + beta[t];
    const float x1 = (hs1 - m) * r * gamma[t + 256] + beta[t + 256];
    sx[t] = x0; sx[t + 256] = x1;
    float dp = x0 * h0 + x1 * h1;
#pragma unroll
    for (int off = 32; off; off >>= 1) dp += __shfl_xor(dp, off, 64);
    if (lane == 0) sred2[wave] = dp;
    __syncthreads();
}

// ---------------------------------------------------------------------------
// K3 bf16 variant: x = LN(...) ; ypout = x @ Abf (RAW partials, bf16 reads)
// ---------------------------------------------------------------------------
__global__ __launch_bounds__(256) void k_mv_bf(
    const u4* __restrict__ Abf, const float* __restrict__ pre,
    const float* __restrict__ h, const float* __restrict__ ypin,
    const float* __restrict__ dotin, const float* __restrict__ gamma,
    const float* __restrict__ beta, float* __restrict__ ypout,
    float* __restrict__ dotout)
{
    const int bc   = blockIdx.x;
    const int b    = bc >> 3;
    const int rs   = bc & 7;
    const int t    = threadIdx.x;
    const int lane = t & 63;
    const int wave = t >> 6;

    __shared__ __align__(16) float sx[UDIM];
    __shared__ __align__(16) float spart[4][UDIM];
    __shared__ float sred[8], sred2[4], sbc[2];

    combine_ln(b, t, lane, wave, pre, h, ypin, dotin, gamma, beta,
               sx, sred, sred2, sbc);
    if (rs == 0 && t == 0)
        dotout[b] = sred2[0] + sred2[1] + sred2[2] + sred2[3];

    // matvec: thread (qtr=t>>6, cg=t&63) -> rows qtr*16..+15, cols cg*8..+7
    const int cg  = t & 63;
    const int qtr = t >> 6;
    const int row0 = rs * RPB + qtr * 16;
    const u4* __restrict__ Ab = Abf + (size_t)(b * UDIM + row0) * (UDIM / 8) + cg;

    float a0=0,a1=0,a2=0,a3=0,a4a=0,a5=0,a6=0,a7=0;
#pragma unroll 4
    for (int k = 0; k < 16; ++k) {
        const u4 q = Ab[(size_t)k * (UDIM / 8)];
        const float xu = sx[row0 + k];
        a0 = fmaf(xu, __uint_as_float(q.x << 16),        a0);
        a1 = fmaf(xu, __uint_as_float(q.x & 0xFFFF0000u), a1);
        a2 = fmaf(xu, __uint_as_float(q.y << 16),        a2);
        a3 = fmaf(xu, __uint_as_float(q.y & 0xFFFF0000u), a3);
        a4a= fmaf(xu, __uint_as_float(q.z << 16),        a4a);
        a5 = fmaf(xu, __uint_as_float(q.z & 0xFFFF0000u), a5);
        a6 = fmaf(xu, __uint_as_float(q.w << 16),        a6);
        a7 = fmaf(xu, __uint_as_float(q.w & 0xFFFF0000u), a7);
    }
    f4 lo = {a0, a1, a2, a3}, hi = {a4a, a5, a6, a7};
    *(f4*)(&spart[qtr][cg * 8])     = lo;
    *(f4*)(&spart[qtr][cg * 8 + 4]) = hi;
    __syncthreads();

    ypout[(size_t)bc * UDIM + t] =
        spart[0][t] + spart[1][t] + spart[2][t] + spart[3][t];
    ypout[(size_t)bc * UDIM + t + 256] =
        spart[0][t+256] + spart[1][t+256] + spart[2][t+256] + spart[3][t+256];
}

// ---------------------------------------------------------------------------
// K3 f32 fallback (ws too small): same, reads A f32
// ---------------------------------------------------------------------------
__global__ __launch_bounds__(256) void k_mv_f32(
    const float* __restrict__ A, const float* __restrict__ pre,
    const float* __restrict__ h, const float* __restrict__ ypin,
    const float* __restrict__ dotin, const float* __restrict__ gamma,
    const float* __restrict__ beta, float* __restrict__ ypout,
    float* __restrict__ dotout)
{
    const int bc   = blockIdx.x;
    const int b    = bc >> 3;
    const int rs   = bc & 7;
    const int t    = threadIdx.x;
    const int lane = t & 63;
    const int wave = t >> 6;
    const int vg   = t & 127;
    const int col  = vg << 2;
    const int half = t >> 7;
    const int row0 = rs * RPB + half * 32;

    __shared__ __align__(16) float sx[UDIM];
    __shared__ __align__(16) float spart[2][UDIM];
    __shared__ float sred[8], sred2[4], sbc[2];

    combine_ln(b, t, lane, wave, pre, h, ypin, dotin, gamma, beta,
               sx, sred, sred2, sbc);
    if (rs == 0 && t == 0)
        dotout[b] = sred2[0] + sred2[1] + sred2[2] + sred2[3];

    const float* __restrict__ Ab = A + ((size_t)b * UDIM + row0) * UDIM + col;
    f4 acc = {0.f, 0.f, 0.f, 0.f};
#pragma unroll 4
    for (int k = 0; k < 32; ++k) {
        const f4 a4 = *(const f4*)(Ab + (size_t)k * UDIM);
        const float xu = sx[row0 + k];
        acc.x = fmaf(xu, a4.x, acc.x);
        acc.y = fmaf(xu, a4.y, acc.y);
        acc.z = fmaf(xu, a4.z, acc.z);
        acc.w = fmaf(xu, a4.w, acc.w);
    }
    *(f4*)(&spart[half][col]) = acc;
    __syncthreads();

    ypout[(size_t)bc * UDIM + t]       = spart[0][t]       + spart[1][t];
    ypout[(size_t)bc * UDIM + t + 256] = spart[0][t + 256] + spart[1][t + 256];
}

// ---------------------------------------------------------------------------
// K4: out = LN(tanh(pre + 0.9*sum yp + 0.5*dot*h))   [proven]
// ---------------------------------------------------------------------------
__global__ __launch_bounds__(512) void k_fin(
    const float* __restrict__ pre, const float* __restrict__ h,
    const float* __restrict__ ypin, const float* __restrict__ dotin,
    const float* __restrict__ gamma, const float* __restrict__ beta,
    float* __restrict__ out)
{
    const int b    = blockIdx.x;
    const int t    = threadIdx.x;
    const int lane = t & 63;
    const int wave = t >> 6;

    __shared__ float sred[16];
    __shared__ float sbc[2];

    float y = 0.f;
#pragma unroll
    for (int s = 0; s < NSLAB; ++s) y += ypin[((size_t)b * NSLAB + s) * UDIM + t];
    y = fmaf(0.9f, y, 0.5f * dotin[b] * h[(size_t)b * UDIM + t]);
    const float hs = tanhf(pre[(size_t)b * UDIM + t] + y);

    float s1 = hs, s2 = hs * hs;
#pragma unroll
    for (int off = 32; off; off >>= 1) {
        s1 += __shfl_xor(s1, off, 64);
        s2 += __shfl_xor(s2, off, 64);
    }
    if (lane == 0) { sred[wave] = s1; sred[8 + wave] = s2; }
    __syncthreads();
    if (t == 0) {
        float m = 0.f, q = 0.f;
#pragma unroll
        for (int i = 0; i < 8; ++i) { m += sred[i]; q += sred[8 + i]; }
        m *= (1.f / UDIM);
        q = q * (1.f / UDIM) - m * m;
        sbc[0] = m;
        sbc[1] = rsqrtf(q + EPSV);
    }
    __syncthreads();
    out[(size_t)b * UDIM + t] = (hs - sbc[0]) * sbc[1] * gamma[t] + beta[t];
}

// ---------------------------------------------------------------------------
extern "C" void kernel_launch(void* const* d_in, const int* in_sizes, int n_in,
                              void* d_out, int out_size, void* d_ws, size_t ws_size,
                              hipStream_t stream) {
    const float* inputs = (const float*)d_in[0];
    const float* prev   = (const float*)d_in[1];
    const float* A      = (const float*)d_in[2];
    const float* C      = (const float*)d_in[3];
    const float* Wh     = (const float*)d_in[4];
    const float* bias   = (const float*)d_in[5];
    const float* gamma  = (const float*)d_in[6];
    const float* beta   = (const float*)d_in[7];

    float* out  = (float*)d_out;                  // (128,512)
    float* Anew = out + (size_t)BATCH * UDIM;     // (128,512,512)

    float* pre  = (float*)d_ws;                          // 65536 f
    float* h    = pre  + (size_t)BATCH * UDIM;           // 65536 f
    float* ypA  = h    + (size_t)BATCH * UDIM;           // 524288 f
    float* ypB  = ypA  + (size_t)BATCH * NSLAB * UDIM;   // 524288 f
    float* dotH = ypB  + (size_t)BATCH * NSLAB * UDIM;   // 128 f
    float* dot1 = dotH + BATCH;
    float* dot2 = dot1 + BATCH;
    char*  abf  = (char*)(dot2 + BATCH);
    // align Abf to 16 B
    size_t aoff = ((size_t)abf + 15) & ~(size_t)15;
    us4*   Abf  = (us4*)aoff;
    const size_t need = (aoff - (size_t)d_ws) + (size_t)BATCH * UDIM * UDIM * 2;
    const bool useBf = (ws_size >= need);

    k_pre<<<BATCH * 2, 256, 0, stream>>>(inputs, prev, C, Wh, bias, pre, h);

    if (useBf) {
        k_p0<1><<<BATCH * NSLAB, 256, 0, stream>>>(A, h, Anew, Abf, ypA, dotH);
        k_mv_bf<<<BATCH * NSLAB, 256, 0, stream>>>((const u4*)Abf, pre, h, ypA,
                                                   dotH, gamma, beta, ypB, dot1);
        k_mv_bf<<<BATCH * NSLAB, 256, 0, stream>>>((const u4*)Abf, pre, h, ypB,
                                                   dot1, gamma, beta, ypA, dot2);
    } else {
        k_p0<0><<<BATCH * NSLAB, 256, 0, stream>>>(A, h, Anew, nullptr, ypA, dotH);
        k_mv_f32<<<BATCH * NSLAB, 256, 0, stream>>>(A, pre, h, ypA,
                                                    dotH, gamma, beta, ypB, dot1);
        k_mv_f32<<<BATCH * NSLAB, 256, 0, stream>>>(A, pre, h, ypB,
                                                    dot1, gamma, beta, ypA, dot2);
    }
    k_fin<<<BATCH, 512, 0, stream>>>(pre, h, ypA, dot2, gamma, beta, out);
}